// Round 4
// baseline (1591.374 us; speedup 1.0000x reference)
//
#include <hip/hip_runtime.h>

// Attention block: x_s = softmax(qk^T)[:4096,4096:] @ query @ Wps^T
//                  x_q = softmax(qk^T)[4096:,:4096] @ s     @ Wpq^T
// bf16 MFMA 16x16x32, fp32 accumulate, XOR-swizzled LDS (R3: conflicts -> 0).
// R4: GEMM1/GEMM2 use 256x128 block tiles with 8 waves (512 thr): B-tile shared,
// barriers/FLOP halved, LDS 48KB -> 3 blocks/CU (24 waves/CU). exp -> v_exp_f32
// with log2(e) folded into q's scale in GEMM1's epilogue. Small kernels fused.

typedef unsigned short u16;
typedef __bf16 bf16x8 __attribute__((ext_vector_type(8)));
typedef float f32x4 __attribute__((ext_vector_type(4)));
typedef unsigned short u16x8 __attribute__((ext_vector_type(8)));

#define DEVI static __device__ __forceinline__

DEVI u16 f2b(float f) {  // fp32 -> bf16 round-to-nearest-even
  unsigned int u = __float_as_uint(f);
  u += 0x7fffu + ((u >> 16) & 1u);
  return (u16)(u >> 16);
}

DEVI float exp2_hw(float x) {  // v_exp_f32: 2^x
  float r;
  asm("v_exp_f32 %0, %1" : "=v"(r) : "v"(x));
  return r;
}

// ---------------- prep kernels ----------------

__global__ void prep_c(const float* __restrict__ query, const float* __restrict__ s,
                       const float* __restrict__ tg, u16* __restrict__ cB) {
  int base = (blockIdx.x * 256 + threadIdx.x) << 3;
  int row = base >> 10;
  u16x8 o;
  if (row < 4096) {
    float4 a0 = *(const float4*)(s + base);
    float4 a1 = *(const float4*)(s + base + 4);
    float4 b0 = *(const float4*)(tg + base);
    float4 b1 = *(const float4*)(tg + base + 4);
    o[0] = f2b(a0.x + b0.x); o[1] = f2b(a0.y + b0.y);
    o[2] = f2b(a0.z + b0.z); o[3] = f2b(a0.w + b0.w);
    o[4] = f2b(a1.x + b1.x); o[5] = f2b(a1.y + b1.y);
    o[6] = f2b(a1.z + b1.z); o[7] = f2b(a1.w + b1.w);
  } else {
    int qb = base - 4096 * 1024;
    float4 a0 = *(const float4*)(query + qb);
    float4 a1 = *(const float4*)(query + qb + 4);
    o[0] = f2b(a0.x); o[1] = f2b(a0.y); o[2] = f2b(a0.z); o[3] = f2b(a0.w);
    o[4] = f2b(a1.x); o[5] = f2b(a1.y); o[6] = f2b(a1.z); o[7] = f2b(a1.w);
  }
  *(u16x8*)(cB + base) = o;
}

// 3 weight conversions in one launch: blocks [0,1024) Wqkv, [1024,1536) Wps, rest Wpq
__global__ void conv3(const float* __restrict__ w0, const float* __restrict__ w1,
                      const float* __restrict__ w2, u16* __restrict__ o0,
                      u16* __restrict__ o1, u16* __restrict__ o2) {
  int b = blockIdx.x;
  const float* in; u16* out; int lb;
  if (b < 1024)      { in = w0; out = o0; lb = b; }
  else if (b < 1536) { in = w1; out = o1; lb = b - 1024; }
  else               { in = w2; out = o2; lb = b - 1536; }
  int base = (lb * 256 + threadIdx.x) << 3;
  float4 a0 = *(const float4*)(in + base);
  float4 a1 = *(const float4*)(in + base + 4);
  u16x8 o;
  o[0] = f2b(a0.x); o[1] = f2b(a0.y); o[2] = f2b(a0.z); o[3] = f2b(a0.w);
  o[4] = f2b(a1.x); o[5] = f2b(a1.y); o[6] = f2b(a1.z); o[7] = f2b(a1.w);
  *(u16x8*)(out + base) = o;
}

// z=0: queryT = query^T, z=1: sT = s^T  (R=4096, C=1024)
__global__ void transpose2(const float* __restrict__ query, const float* __restrict__ s,
                           u16* __restrict__ queryT, u16* __restrict__ sT) {
  __shared__ float tile[32][33];
  const float* in = blockIdx.z ? s : query;
  u16* out = blockIdx.z ? sT : queryT;
  int c0 = blockIdx.x * 32, r0 = blockIdx.y * 32;
  int tx = threadIdx.x, ty = threadIdx.y;  // blockDim (32,8)
#pragma unroll
  for (int i = 0; i < 4; ++i)
    tile[ty + i * 8][tx] = in[(size_t)(r0 + ty + i * 8) * 1024 + c0 + tx];
  __syncthreads();
#pragma unroll
  for (int i = 0; i < 4; ++i)
    out[(size_t)(c0 + ty + i * 8) * 4096 + r0 + tx] = f2b(tile[tx][ty + i * 8]);
}

// ---------------- 256x128-tile GEMM, 8 waves: C[M,N] = A[M,K] @ B[N,K]^T ----
// EPI 0: outb = bf16(acc * (col<1024 ? sq : sk))   (q|k projection)
// EPI 1: exp2 + quadrant bf16 store + rowsum atomics (scores, pre-scaled log2e)

template <int EPI>
__global__ __launch_bounds__(512, 6)
void gemm_big(const u16* __restrict__ A, const u16* __restrict__ B,
              int lda, int ldb, int K, int ldc,
              u16* __restrict__ outb, float sq, float sk,
              u16* __restrict__ Pcq, u16* __restrict__ Pqc,
              float* __restrict__ rowsum) {
  __shared__ __align__(16) u16 sA[256 * 64];  // 32 KB
  __shared__ __align__(16) u16 sB[128 * 64];  // 16 KB
  const int tid = threadIdx.x;
  const int lane = tid & 63;
  const int wave = tid >> 6;                 // 0..7
  const int wr = (wave >> 1) * 64;           // 0,64,128,192
  const int wc = (wave & 1) * 64;            // 0,64
  const int ar = lane & 15;
  const int by = blockIdx.y, bx = blockIdx.x;

  const u16* Ab = A + (size_t)(by * 256) * lda;
  const u16* Bb = B + (size_t)(bx * 128) * ldb;

  f32x4 zero = {0.0f, 0.0f, 0.0f, 0.0f};
  f32x4 acc[4][4];
#pragma unroll
  for (int i = 0; i < 4; ++i)
#pragma unroll
    for (int j = 0; j < 4; ++j) acc[i][j] = zero;

  const int sr = tid >> 3;                        // 0..63
  const int scL = (tid & 7) << 3;                 // LDS dst col (lane*16B forced)
  const int scG = ((tid & 7) ^ (sr & 7)) << 3;    // swizzled global col granule

  for (int k0 = 0; k0 < K; k0 += 64) {
#pragma unroll
    for (int it = 0; it < 4; ++it) {
      int r = it * 64 + sr;
      __builtin_amdgcn_global_load_lds(
          (__attribute__((address_space(1))) void*)(Ab + (size_t)r * lda + k0 + scG),
          (__attribute__((address_space(3))) void*)(sA + r * 64 + scL), 16, 0, 0);
    }
#pragma unroll
    for (int it = 0; it < 2; ++it) {
      int r = it * 64 + sr;
      __builtin_amdgcn_global_load_lds(
          (__attribute__((address_space(1))) void*)(Bb + (size_t)r * ldb + k0 + scG),
          (__attribute__((address_space(3))) void*)(sB + r * 64 + scL), 16, 0, 0);
    }
    __syncthreads();
#pragma unroll
    for (int kk = 0; kk < 64; kk += 32) {
      const int gl = (kk >> 3) + (lane >> 4);
      bf16x8 af[4], bfr[4];
#pragma unroll
      for (int t = 0; t < 4; ++t) {
        const int row = wr + t * 16 + ar;
        af[t] = *(const bf16x8*)(sA + row * 64 + ((gl ^ (row & 7)) << 3));
      }
#pragma unroll
      for (int t = 0; t < 4; ++t) {
        const int row = wc + t * 16 + ar;
        bfr[t] = *(const bf16x8*)(sB + row * 64 + ((gl ^ (row & 7)) << 3));
      }
#pragma unroll
      for (int tm = 0; tm < 4; ++tm)
#pragma unroll
        for (int tn = 0; tn < 4; ++tn)
          acc[tm][tn] = __builtin_amdgcn_mfma_f32_16x16x32_bf16(
              af[tm], bfr[tn], acc[tm][tn], 0, 0, 0);
    }
    __syncthreads();
  }

  // C/D layout (m89): row=(lane>>4)*4+reg, col=lane&15.
  const int qr = (lane >> 4) * 4;
  const int qc = lane & 15;

  if constexpr (EPI == 0) {
#pragma unroll
    for (int tm = 0; tm < 4; ++tm)
#pragma unroll
      for (int r = 0; r < 4; ++r) {
        int row = by * 256 + wr + tm * 16 + qr + r;
#pragma unroll
        for (int tn = 0; tn < 4; ++tn) {
          int col = bx * 128 + wc + tn * 16 + qc;
          float sc = (col < 1024) ? sq : sk;
          outb[(size_t)row * ldc + col] = f2b(acc[tm][tn][r] * sc);
        }
      }
  } else {
    const bool top = (by < 16);
    const bool left = (bx < 32);
    u16* pdst = nullptr;
    if (top && !left) pdst = Pcq;
    if (!top && left) pdst = Pqc;
    const int rofs = top ? 0 : 4096;
    const int cofs = left ? 0 : 4096;
#pragma unroll
    for (int tm = 0; tm < 4; ++tm) {
      float rsum[4] = {0.f, 0.f, 0.f, 0.f};
#pragma unroll
      for (int tn = 0; tn < 4; ++tn) {
        float e[4];
#pragma unroll
        for (int r = 0; r < 4; ++r) {
          e[r] = exp2_hw(acc[tm][tn][r]);  // scores pre-scaled by log2(e)
          rsum[r] += e[r];
        }
        if (pdst) {
          int col = bx * 128 + wc + tn * 16 + qc - cofs;
#pragma unroll
          for (int r = 0; r < 4; ++r) {
            int row = by * 256 + wr + tm * 16 + qr + r - rofs;
            pdst[(size_t)row * 4096 + col] = f2b(e[r]);
          }
        }
      }
#pragma unroll
      for (int r = 0; r < 4; ++r) {
        float v = rsum[r];
        v += __shfl_xor(v, 1);
        v += __shfl_xor(v, 2);
        v += __shfl_xor(v, 4);
        v += __shfl_xor(v, 8);
        if ((lane & 15) == 0)
          atomicAdd(&rowsum[by * 256 + wr + tm * 16 + qr + r], v);
      }
    }
  }
}

// ---------------- 128x128-tile GEMM, 4 waves (PV + out-proj) ----------------
// EPI 2: outb = bf16(acc / rs[row])   z-batched
// EPI 3: outf = acc                   z-batched

template <int EPI>
__global__ __launch_bounds__(256)
void gemm_bt(const u16* __restrict__ A, const u16* __restrict__ A1,
             const u16* __restrict__ B, const u16* __restrict__ B1,
             int lda, int ldb, int K, int ldc,
             u16* __restrict__ outb, u16* __restrict__ outb1,
             float* __restrict__ outf, float* __restrict__ outf1,
             const float* __restrict__ rs, const float* __restrict__ rs1) {
  __shared__ __align__(16) u16 sA[128 * 64];
  __shared__ __align__(16) u16 sB[128 * 64];
  const int tid = threadIdx.x;
  const int lane = tid & 63;
  const int wave = tid >> 6;
  const int wr = (wave >> 1) * 64;
  const int wc = (wave & 1) * 64;
  const int ar = lane & 15;
  const int by = blockIdx.y, bx = blockIdx.x;
  const int z = blockIdx.z;

  const u16* Ab = (z ? A1 : A) + (size_t)(by * 128) * lda;
  const u16* Bb = (z ? B1 : B) + (size_t)(bx * 128) * ldb;

  f32x4 zero = {0.0f, 0.0f, 0.0f, 0.0f};
  f32x4 acc[4][4];
#pragma unroll
  for (int i = 0; i < 4; ++i)
#pragma unroll
    for (int j = 0; j < 4; ++j) acc[i][j] = zero;

  const int sr = tid >> 3;
  const int scL = (tid & 7) << 3;
  const int scG = ((tid & 7) ^ (sr & 7)) << 3;

  for (int k0 = 0; k0 < K; k0 += 64) {
#pragma unroll
    for (int it = 0; it < 4; ++it) {
      int r = it * 32 + sr;
      __builtin_amdgcn_global_load_lds(
          (__attribute__((address_space(1))) void*)(Ab + (size_t)r * lda + k0 + scG),
          (__attribute__((address_space(3))) void*)(sA + r * 64 + scL), 16, 0, 0);
    }
#pragma unroll
    for (int it = 0; it < 4; ++it) {
      int r = it * 32 + sr;
      __builtin_amdgcn_global_load_lds(
          (__attribute__((address_space(1))) void*)(Bb + (size_t)r * ldb + k0 + scG),
          (__attribute__((address_space(3))) void*)(sB + r * 64 + scL), 16, 0, 0);
    }
    __syncthreads();
#pragma unroll
    for (int kk = 0; kk < 64; kk += 32) {
      const int gl = (kk >> 3) + (lane >> 4);
      bf16x8 af[4], bfr[4];
#pragma unroll
      for (int t = 0; t < 4; ++t) {
        const int row = wr + t * 16 + ar;
        af[t] = *(const bf16x8*)(sA + row * 64 + ((gl ^ (row & 7)) << 3));
      }
#pragma unroll
      for (int t = 0; t < 4; ++t) {
        const int row = wc + t * 16 + ar;
        bfr[t] = *(const bf16x8*)(sB + row * 64 + ((gl ^ (row & 7)) << 3));
      }
#pragma unroll
      for (int tm = 0; tm < 4; ++tm)
#pragma unroll
        for (int tn = 0; tn < 4; ++tn)
          acc[tm][tn] = __builtin_amdgcn_mfma_f32_16x16x32_bf16(
              af[tm], bfr[tn], acc[tm][tn], 0, 0, 0);
    }
    __syncthreads();
  }

  const int qr = (lane >> 4) * 4;
  const int qc = lane & 15;

  if constexpr (EPI == 2) {
    u16* ob = z ? outb1 : outb;
    const float* rsz = z ? rs1 : rs;
#pragma unroll
    for (int tm = 0; tm < 4; ++tm)
#pragma unroll
      for (int r = 0; r < 4; ++r) {
        int row = by * 128 + wr + tm * 16 + qr + r;
        float inv = 1.0f / rsz[row];
#pragma unroll
        for (int tn = 0; tn < 4; ++tn) {
          int col = bx * 128 + wc + tn * 16 + qc;
          ob[(size_t)row * ldc + col] = f2b(acc[tm][tn][r] * inv);
        }
      }
  } else {
    float* of = z ? outf1 : outf;
#pragma unroll
    for (int tm = 0; tm < 4; ++tm)
#pragma unroll
      for (int r = 0; r < 4; ++r) {
        int row = by * 128 + wr + tm * 16 + qr + r;
#pragma unroll
        for (int tn = 0; tn < 4; ++tn) {
          int col = bx * 128 + wc + tn * 16 + qc;
          of[(size_t)row * ldc + col] = acc[tm][tn][r];
        }
      }
  }
}

// ---------------- launcher ----------------

extern "C" void kernel_launch(void* const* d_in, const int* in_sizes, int n_in,
                              void* d_out, int out_size, void* d_ws, size_t ws_size,
                              hipStream_t stream) {
  (void)in_sizes; (void)n_in; (void)out_size; (void)ws_size;
  const float* query = (const float*)d_in[0];
  const float* s     = (const float*)d_in[1];
  const float* tg    = (const float*)d_in[2];
  const float* Wqkv  = (const float*)d_in[3];
  const float* Wps   = (const float*)d_in[4];
  const float* Wpq   = (const float*)d_in[5];
  float* out = (float*)d_out;

  char* ws = (char*)d_ws;
  u16* cB     = (u16*)ws; ws += (size_t)8192 * 1024 * 2;
  u16* qks    = (u16*)ws; ws += (size_t)8192 * 2048 * 2;
  u16* queryT = (u16*)ws; ws += (size_t)1024 * 4096 * 2;
  u16* sT     = (u16*)ws; ws += (size_t)1024 * 4096 * 2;
  u16* WqkB   = (u16*)ws; ws += (size_t)2048 * 1024 * 2;
  u16* WpsB   = (u16*)ws; ws += (size_t)1024 * 1024 * 2;
  u16* WpqB   = (u16*)ws; ws += (size_t)1024 * 1024 * 2;
  u16* Pcq    = (u16*)ws; ws += (size_t)4096 * 4096 * 2;
  u16* Pqc    = (u16*)ws; ws += (size_t)4096 * 4096 * 2;
  u16* Ys     = (u16*)ws; ws += (size_t)4096 * 1024 * 2;
  u16* Yq     = (u16*)ws; ws += (size_t)4096 * 1024 * 2;
  float* rowsum = (float*)ws;  // 8192 floats

  const float SCALE = 0.17677669529663687f;   // 1024^-0.25
  const float LOG2E = 1.4426950408889634f;

  (void)hipMemsetAsync(rowsum, 0, 8192 * sizeof(float), stream);
  prep_c<<<4096, 256, 0, stream>>>(query, s, tg, cB);
  conv3<<<2048, 256, 0, stream>>>(Wqkv, Wps, Wpq, WqkB, WpsB, WpqB);
  transpose2<<<dim3(32, 128, 2), dim3(32, 8), 0, stream>>>(query, s, queryT, sT);

  // GEMM1: qks[8192,2048] = cB @ WqkB^T; q cols scaled SCALE*LOG2E, k cols SCALE
  gemm_big<0><<<dim3(16, 32), 512, 0, stream>>>(
      cB, WqkB, 1024, 1024, 1024, 2048,
      qks, SCALE * LOG2E, SCALE, nullptr, nullptr, nullptr);
  // GEMM2: scores (8192x8192) -> 2^score quadrants (bf16) + row sums
  gemm_big<1><<<dim3(64, 32), 512, 0, stream>>>(
      qks, qks + 1024, 2048, 2048, 1024, 0,
      nullptr, 0.f, 0.f, Pcq, Pqc, rowsum);
  // GEMM3 (z-batched): Ys = (Pcq@query)/rs ; Yq = (Pqc@s)/rs
  gemm_bt<2><<<dim3(8, 32, 2), 256, 0, stream>>>(
      Pcq, Pqc, queryT, sT, 4096, 4096, 4096, 1024,
      Ys, Yq, nullptr, nullptr, rowsum, rowsum + 4096);
  // GEMM4 (z-batched): out = [Ys@Wps^T ; Yq@Wpq^T] (fp32)
  gemm_bt<3><<<dim3(8, 32, 2), 256, 0, stream>>>(
      Ys, Yq, WpsB, WpqB, 1024, 1024, 1024, 1024,
      nullptr, nullptr, out, out + (size_t)4096 * 1024, nullptr, nullptr);
}

// Round 5
// 479.433 us; speedup vs baseline: 3.3193x; 3.3193x over previous
//
#include <hip/hip_runtime.h>

// Attention block: x_s = softmax(qk^T)[:4096,4096:] @ query @ Wps^T
//                  x_q = softmax(qk^T)[4096:,:4096] @ s     @ Wpq^T
// bf16 MFMA 16x16x32, fp32 acc, XOR-swizzled LDS (R3: bank conflicts -> 0).
// R5: revert to proven 128x128/4-wave tile (R4's 256x128@launch_bounds(512,6)
// spilled accumulators -> 5.4GB scratch traffic). New: LDS fragment addresses
// hoisted to 2 vaddrs/operand (t*2048 + sB base go in ds_read offset imm);
// exp->2^x fold (LOG2E into GEMM1 q-scale, v_exp_f32 in score epilogue);
// fused prep kernels. NEVER cap launch_bounds below acc+frag footprint.

typedef unsigned short u16;
typedef __bf16 bf16x8 __attribute__((ext_vector_type(8)));
typedef float f32x4 __attribute__((ext_vector_type(4)));
typedef unsigned short u16x8 __attribute__((ext_vector_type(8)));

#define DEVI static __device__ __forceinline__

DEVI u16 f2b(float f) {  // fp32 -> bf16 round-to-nearest-even
  unsigned int u = __float_as_uint(f);
  u += 0x7fffu + ((u >> 16) & 1u);
  return (u16)(u >> 16);
}

DEVI float exp2_hw(float x) {  // v_exp_f32: 2^x
  float r;
  asm("v_exp_f32 %0, %1" : "=v"(r) : "v"(x));
  return r;
}

// ---------------- prep kernels ----------------

__global__ void prep_c(const float* __restrict__ query, const float* __restrict__ s,
                       const float* __restrict__ tg, u16* __restrict__ cB) {
  int base = (blockIdx.x * 256 + threadIdx.x) << 3;
  int row = base >> 10;
  u16x8 o;
  if (row < 4096) {
    float4 a0 = *(const float4*)(s + base);
    float4 a1 = *(const float4*)(s + base + 4);
    float4 b0 = *(const float4*)(tg + base);
    float4 b1 = *(const float4*)(tg + base + 4);
    o[0] = f2b(a0.x + b0.x); o[1] = f2b(a0.y + b0.y);
    o[2] = f2b(a0.z + b0.z); o[3] = f2b(a0.w + b0.w);
    o[4] = f2b(a1.x + b1.x); o[5] = f2b(a1.y + b1.y);
    o[6] = f2b(a1.z + b1.z); o[7] = f2b(a1.w + b1.w);
  } else {
    int qb = base - 4096 * 1024;
    float4 a0 = *(const float4*)(query + qb);
    float4 a1 = *(const float4*)(query + qb + 4);
    o[0] = f2b(a0.x); o[1] = f2b(a0.y); o[2] = f2b(a0.z); o[3] = f2b(a0.w);
    o[4] = f2b(a1.x); o[5] = f2b(a1.y); o[6] = f2b(a1.z); o[7] = f2b(a1.w);
  }
  *(u16x8*)(cB + base) = o;
}

// 3 weight conversions in one launch: blocks [0,1024) Wqkv(q,k), [1024,1536) Wps, rest Wpq
__global__ void conv3(const float* __restrict__ w0, const float* __restrict__ w1,
                      const float* __restrict__ w2, u16* __restrict__ o0,
                      u16* __restrict__ o1, u16* __restrict__ o2) {
  int b = blockIdx.x;
  const float* in; u16* out; int lb;
  if (b < 1024)      { in = w0; out = o0; lb = b; }
  else if (b < 1536) { in = w1; out = o1; lb = b - 1024; }
  else               { in = w2; out = o2; lb = b - 1536; }
  int base = (lb * 256 + threadIdx.x) << 3;
  float4 a0 = *(const float4*)(in + base);
  float4 a1 = *(const float4*)(in + base + 4);
  u16x8 o;
  o[0] = f2b(a0.x); o[1] = f2b(a0.y); o[2] = f2b(a0.z); o[3] = f2b(a0.w);
  o[4] = f2b(a1.x); o[5] = f2b(a1.y); o[6] = f2b(a1.z); o[7] = f2b(a1.w);
  *(u16x8*)(out + base) = o;
}

// z=0: queryT = query^T, z=1: sT = s^T  (4096x1024 -> 1024x4096 bf16)
__global__ void transpose2(const float* __restrict__ query, const float* __restrict__ s,
                           u16* __restrict__ queryT, u16* __restrict__ sT) {
  __shared__ float tile[32][33];
  const float* in = blockIdx.z ? s : query;
  u16* out = blockIdx.z ? sT : queryT;
  int c0 = blockIdx.x * 32, r0 = blockIdx.y * 32;
  int tx = threadIdx.x, ty = threadIdx.y;  // blockDim (32,8)
#pragma unroll
  for (int i = 0; i < 4; ++i)
    tile[ty + i * 8][tx] = in[(size_t)(r0 + ty + i * 8) * 1024 + c0 + tx];
  __syncthreads();
#pragma unroll
  for (int i = 0; i < 4; ++i)
    out[(size_t)(c0 + ty + i * 8) * 4096 + r0 + tx] = f2b(tile[tx][ty + i * 8]);
}

// ---------------- 128x128-tile GEMM, 4 waves: C[M,N] = A[M,K] @ B[N,K]^T ----
// EPI 0: outb = bf16(acc * (col<1024 ? sq : sk))     (q|k projection)
// EPI 1: 2^acc + quadrant bf16 store + rowsum atomics (scores, pre-scaled log2e)
// EPI 2: outb = bf16(acc / rs[row])   z-batched
// EPI 3: outf = acc                   z-batched

template <int EPI>
__global__ __launch_bounds__(256)
void gemm_bt(const u16* __restrict__ A, const u16* __restrict__ A1,
             const u16* __restrict__ B, const u16* __restrict__ B1,
             int lda, int ldb, int K, int ldc,
             u16* __restrict__ outb, u16* __restrict__ outb1,
             float* __restrict__ outf, float* __restrict__ outf1,
             float sq, float sk,
             const float* __restrict__ rs, const float* __restrict__ rs1,
             u16* __restrict__ Pcq, u16* __restrict__ Pqc,
             float* __restrict__ rowsum) {
  __shared__ __align__(16) u16 sA[128 * 64];
  __shared__ __align__(16) u16 sB[128 * 64];
  const int tid = threadIdx.x;
  const int lane = tid & 63;
  const int wave = tid >> 6;
  const int wr = (wave >> 1) * 64;
  const int wc = (wave & 1) * 64;
  const int ar = lane & 15;
  const int by = blockIdx.y, bx = blockIdx.x;
  const int z = (EPI == 2 || EPI == 3) ? blockIdx.z : 0;

  const u16* Ab = (z ? A1 : A) + (size_t)(by * 128) * lda;
  const u16* Bb = (z ? B1 : B) + (size_t)(bx * 128) * ldb;

  f32x4 zero = {0.0f, 0.0f, 0.0f, 0.0f};
  f32x4 acc[4][4];
#pragma unroll
  for (int i = 0; i < 4; ++i)
#pragma unroll
    for (int j = 0; j < 4; ++j) acc[i][j] = zero;

  const int sr = tid >> 3;                        // 0..31 (row within 32-row group)
  const int scL = (tid & 7) << 3;                 // LDS dst col (lane*16B forced)
  const int scG = ((tid & 7) ^ (sr & 7)) << 3;    // swizzled global col granule

  // Hoisted, loop-invariant LDS fragment byte offsets.
  // Logical granule gl = (kk>>3) + (lane>>4); physical = gl ^ (row&7),
  // row&7 == lane&7 for every fragment row. kk=32 flips granule bit 2 -> ^64 bytes.
  const int l7 = lane & 7, l16 = lane >> 4;
  const int p0b = (l16 ^ l7) << 4;                // byte offset of kk=0 granule
  const int offA0 = (wr + ar) * 128 + p0b;        // + t*2048 via imm
  const int offB0 = (wc + ar) * 128 + p0b;
  const char* sAc = (const char*)sA;
  const char* sBc = (const char*)sB;

  for (int k0 = 0; k0 < K; k0 += 64) {
#pragma unroll
    for (int it = 0; it < 4; ++it) {
      int r = it * 32 + sr;
      __builtin_amdgcn_global_load_lds(
          (__attribute__((address_space(1))) void*)(Ab + (size_t)r * lda + k0 + scG),
          (__attribute__((address_space(3))) void*)(sA + r * 64 + scL), 16, 0, 0);
    }
#pragma unroll
    for (int it = 0; it < 4; ++it) {
      int r = it * 32 + sr;
      __builtin_amdgcn_global_load_lds(
          (__attribute__((address_space(1))) void*)(Bb + (size_t)r * ldb + k0 + scG),
          (__attribute__((address_space(3))) void*)(sB + r * 64 + scL), 16, 0, 0);
    }
    __syncthreads();
#pragma unroll
    for (int half = 0; half < 2; ++half) {
      const int px = half ? 64 : 0;  // kk=32 -> ^64 bytes (bit 6 lives in p0b)
      bf16x8 af[4], bfr[4];
#pragma unroll
      for (int t = 0; t < 4; ++t)
        af[t] = *(const bf16x8*)(sAc + ((offA0 ^ px) + t * 2048));
#pragma unroll
      for (int t = 0; t < 4; ++t)
        bfr[t] = *(const bf16x8*)(sBc + ((offB0 ^ px) + t * 2048));
#pragma unroll
      for (int tm = 0; tm < 4; ++tm)
#pragma unroll
        for (int tn = 0; tn < 4; ++tn)
          acc[tm][tn] = __builtin_amdgcn_mfma_f32_16x16x32_bf16(
              af[tm], bfr[tn], acc[tm][tn], 0, 0, 0);
    }
    __syncthreads();
  }

  // Epilogue. C/D layout (m89): row=(lane>>4)*4+reg, col=lane&15.
  const int qr = (lane >> 4) * 4;
  const int qc = lane & 15;

  if constexpr (EPI == 0) {
#pragma unroll
    for (int tm = 0; tm < 4; ++tm)
#pragma unroll
      for (int r = 0; r < 4; ++r) {
        int row = by * 128 + wr + tm * 16 + qr + r;
#pragma unroll
        for (int tn = 0; tn < 4; ++tn) {
          int col = bx * 128 + wc + tn * 16 + qc;
          float sc = (col < 1024) ? sq : sk;
          outb[(size_t)row * ldc + col] = f2b(acc[tm][tn][r] * sc);
        }
      }
  } else if constexpr (EPI == 1) {
    const bool top = (by < 32);
    const bool left = (bx < 32);
    u16* pdst = nullptr;
    if (top && !left) pdst = Pcq;
    if (!top && left) pdst = Pqc;
    const int rofs = top ? 0 : 4096;
    const int cofs = left ? 0 : 4096;
#pragma unroll
    for (int tm = 0; tm < 4; ++tm) {
      float rsum[4] = {0.f, 0.f, 0.f, 0.f};
#pragma unroll
      for (int tn = 0; tn < 4; ++tn) {
        float e[4];
#pragma unroll
        for (int r = 0; r < 4; ++r) {
          e[r] = exp2_hw(acc[tm][tn][r]);  // scores pre-scaled by log2(e)
          rsum[r] += e[r];
        }
        if (pdst) {
          int col = bx * 128 + wc + tn * 16 + qc - cofs;
#pragma unroll
          for (int r = 0; r < 4; ++r) {
            int row = by * 128 + wr + tm * 16 + qr + r - rofs;
            pdst[(size_t)row * 4096 + col] = f2b(e[r]);
          }
        }
      }
#pragma unroll
      for (int r = 0; r < 4; ++r) {
        float v = rsum[r];
        v += __shfl_xor(v, 1);
        v += __shfl_xor(v, 2);
        v += __shfl_xor(v, 4);
        v += __shfl_xor(v, 8);
        if ((lane & 15) == 0)
          atomicAdd(&rowsum[by * 128 + wr + tm * 16 + qr + r], v);
      }
    }
  } else if constexpr (EPI == 2) {
    u16* ob = z ? outb1 : outb;
    const float* rsz = z ? rs1 : rs;
#pragma unroll
    for (int tm = 0; tm < 4; ++tm)
#pragma unroll
      for (int r = 0; r < 4; ++r) {
        int row = by * 128 + wr + tm * 16 + qr + r;
        float inv = 1.0f / rsz[row];
#pragma unroll
        for (int tn = 0; tn < 4; ++tn) {
          int col = bx * 128 + wc + tn * 16 + qc;
          ob[(size_t)row * ldc + col] = f2b(acc[tm][tn][r] * inv);
        }
      }
  } else {
    float* of = z ? outf1 : outf;
#pragma unroll
    for (int tm = 0; tm < 4; ++tm)
#pragma unroll
      for (int r = 0; r < 4; ++r) {
        int row = by * 128 + wr + tm * 16 + qr + r;
#pragma unroll
        for (int tn = 0; tn < 4; ++tn) {
          int col = bx * 128 + wc + tn * 16 + qc;
          of[(size_t)row * ldc + col] = acc[tm][tn][r];
        }
      }
  }
}

// ---------------- launcher ----------------

extern "C" void kernel_launch(void* const* d_in, const int* in_sizes, int n_in,
                              void* d_out, int out_size, void* d_ws, size_t ws_size,
                              hipStream_t stream) {
  (void)in_sizes; (void)n_in; (void)out_size; (void)ws_size;
  const float* query = (const float*)d_in[0];
  const float* s     = (const float*)d_in[1];
  const float* tg    = (const float*)d_in[2];
  const float* Wqkv  = (const float*)d_in[3];
  const float* Wps   = (const float*)d_in[4];
  const float* Wpq   = (const float*)d_in[5];
  float* out = (float*)d_out;

  char* ws = (char*)d_ws;
  u16* cB     = (u16*)ws; ws += (size_t)8192 * 1024 * 2;
  u16* qks    = (u16*)ws; ws += (size_t)8192 * 2048 * 2;
  u16* queryT = (u16*)ws; ws += (size_t)1024 * 4096 * 2;
  u16* sT     = (u16*)ws; ws += (size_t)1024 * 4096 * 2;
  u16* WqkB   = (u16*)ws; ws += (size_t)2048 * 1024 * 2;
  u16* WpsB   = (u16*)ws; ws += (size_t)1024 * 1024 * 2;
  u16* WpqB   = (u16*)ws; ws += (size_t)1024 * 1024 * 2;
  u16* Pcq    = (u16*)ws; ws += (size_t)4096 * 4096 * 2;
  u16* Pqc    = (u16*)ws; ws += (size_t)4096 * 4096 * 2;
  u16* Ys     = (u16*)ws; ws += (size_t)4096 * 1024 * 2;
  u16* Yq     = (u16*)ws; ws += (size_t)4096 * 1024 * 2;
  float* rowsum = (float*)ws;  // 8192 floats

  const float SCALE = 0.17677669529663687f;   // 1024^-0.25
  const float LOG2E = 1.4426950408889634f;

  (void)hipMemsetAsync(rowsum, 0, 8192 * sizeof(float), stream);
  prep_c<<<4096, 256, 0, stream>>>(query, s, tg, cB);
  conv3<<<2048, 256, 0, stream>>>(Wqkv, Wps, Wpq, WqkB, WpsB, WpqB);
  transpose2<<<dim3(32, 128, 2), dim3(32, 8), 0, stream>>>(query, s, queryT, sT);

  // GEMM1: qks[8192,2048] = cB @ WqkB^T; q cols scaled SCALE*LOG2E, k cols SCALE
  gemm_bt<0><<<dim3(16, 64), 256, 0, stream>>>(
      cB, nullptr, WqkB, nullptr, 1024, 1024, 1024, 2048,
      qks, nullptr, nullptr, nullptr, SCALE * LOG2E, SCALE,
      nullptr, nullptr, nullptr, nullptr, nullptr);
  // GEMM2: scores (8192x8192) -> 2^score quadrants (bf16) + row sums
  gemm_bt<1><<<dim3(64, 64), 256, 0, stream>>>(
      qks, nullptr, qks + 1024, nullptr, 2048, 2048, 1024, 0,
      nullptr, nullptr, nullptr, nullptr, 0.f, 0.f,
      nullptr, nullptr, Pcq, Pqc, rowsum);
  // GEMM3 (z-batched): Ys = (Pcq@query)/rs ; Yq = (Pqc@s)/rs
  gemm_bt<2><<<dim3(8, 32, 2), 256, 0, stream>>>(
      Pcq, Pqc, queryT, sT, 4096, 4096, 4096, 1024,
      Ys, Yq, nullptr, nullptr, 0.f, 0.f,
      rowsum, rowsum + 4096, nullptr, nullptr, nullptr);
  // GEMM4 (z-batched): out = [Ys@Wps^T ; Yq@Wpq^T] (fp32)
  gemm_bt<3><<<dim3(8, 32, 2), 256, 0, stream>>>(
      Ys, Yq, WpsB, WpqB, 1024, 1024, 1024, 1024,
      nullptr, nullptr, out, out + (size_t)4096 * 1024, 0.f, 0.f,
      nullptr, nullptr, nullptr, nullptr, nullptr);
}

// Round 6
// 458.223 us; speedup vs baseline: 3.4729x; 1.0463x over previous
//
#include <hip/hip_runtime.h>

// Attention block: x_s = softmax(qk^T)[:4096,4096:] @ query @ Wps^T
//                  x_q = softmax(qk^T)[4096:,:4096] @ s     @ Wpq^T
// bf16 MFMA 16x16x32, fp32 acc, XOR-swizzled LDS (R3: bank conflicts -> 0),
// hoisted LDS frag addressing (R5). R6:
//  (a) EPI1 stores coalesced via wave-private LDS transpose (16 scalar 2B
//      stores/tm -> 2 dwordx4), exploiting dead sA after the last barrier.
//  (b) re-associate (P@query)@Wps^T = P@(query@Wps^T): precompute
//      V'^T = Wproj@input^T (z-batched), PV GEMM writes fp32/rowsum straight
//      to d_out. Deletes GEMM4 + both transposes + Y round-trip.

typedef unsigned short u16;
typedef __bf16 bf16x8 __attribute__((ext_vector_type(8)));
typedef float f32x4 __attribute__((ext_vector_type(4)));
typedef unsigned short u16x8 __attribute__((ext_vector_type(8)));

#define DEVI static __device__ __forceinline__

DEVI u16 f2b(float f) {  // fp32 -> bf16 round-to-nearest-even
  unsigned int u = __float_as_uint(f);
  u += 0x7fffu + ((u >> 16) & 1u);
  return (u16)(u >> 16);
}

DEVI float exp2_hw(float x) {  // v_exp_f32: 2^x
  float r;
  asm("v_exp_f32 %0, %1" : "=v"(r) : "v"(x));
  return r;
}

// ---------------- prep kernels ----------------

// cB (8192x1024): rows 0..4095 = bf16(s+TG), rows 4096.. = bf16(query).
// sBf (4096x1024) = bf16(s)  (B-operand for V'q = Wpq@s^T).
__global__ void prep_c(const float* __restrict__ query, const float* __restrict__ s,
                       const float* __restrict__ tg, u16* __restrict__ cB,
                       u16* __restrict__ sBf) {
  int base = (blockIdx.x * 256 + threadIdx.x) << 3;
  int row = base >> 10;
  u16x8 o;
  if (row < 4096) {
    float4 a0 = *(const float4*)(s + base);
    float4 a1 = *(const float4*)(s + base + 4);
    float4 b0 = *(const float4*)(tg + base);
    float4 b1 = *(const float4*)(tg + base + 4);
    u16x8 os;
    os[0] = f2b(a0.x); os[1] = f2b(a0.y); os[2] = f2b(a0.z); os[3] = f2b(a0.w);
    os[4] = f2b(a1.x); os[5] = f2b(a1.y); os[6] = f2b(a1.z); os[7] = f2b(a1.w);
    *(u16x8*)(sBf + base) = os;
    o[0] = f2b(a0.x + b0.x); o[1] = f2b(a0.y + b0.y);
    o[2] = f2b(a0.z + b0.z); o[3] = f2b(a0.w + b0.w);
    o[4] = f2b(a1.x + b1.x); o[5] = f2b(a1.y + b1.y);
    o[6] = f2b(a1.z + b1.z); o[7] = f2b(a1.w + b1.w);
  } else {
    int qb = base - 4096 * 1024;
    float4 a0 = *(const float4*)(query + qb);
    float4 a1 = *(const float4*)(query + qb + 4);
    o[0] = f2b(a0.x); o[1] = f2b(a0.y); o[2] = f2b(a0.z); o[3] = f2b(a0.w);
    o[4] = f2b(a1.x); o[5] = f2b(a1.y); o[6] = f2b(a1.z); o[7] = f2b(a1.w);
  }
  *(u16x8*)(cB + base) = o;
}

// 3 weight conversions: blocks [0,1024) Wqkv(q,k rows), [1024,1536) Wps, rest Wpq
__global__ void conv3(const float* __restrict__ w0, const float* __restrict__ w1,
                      const float* __restrict__ w2, u16* __restrict__ o0,
                      u16* __restrict__ o1, u16* __restrict__ o2) {
  int b = blockIdx.x;
  const float* in; u16* out; int lb;
  if (b < 1024)      { in = w0; out = o0; lb = b; }
  else if (b < 1536) { in = w1; out = o1; lb = b - 1024; }
  else               { in = w2; out = o2; lb = b - 1536; }
  int base = (lb * 256 + threadIdx.x) << 3;
  float4 a0 = *(const float4*)(in + base);
  float4 a1 = *(const float4*)(in + base + 4);
  u16x8 o;
  o[0] = f2b(a0.x); o[1] = f2b(a0.y); o[2] = f2b(a0.z); o[3] = f2b(a0.w);
  o[4] = f2b(a1.x); o[5] = f2b(a1.y); o[6] = f2b(a1.z); o[7] = f2b(a1.w);
  *(u16x8*)(out + base) = o;
}

// ---------------- 128x128-tile GEMM, 4 waves: C[M,N] = A[M,K] @ B[N,K]^T ----
// EPI 0: outb = bf16(acc * (col<1024 ? sq : sk))      (q|k projection)
// EPI 1: 2^acc, coalesced quadrant store, rowsum atomics (scores)
// EPI 4: outf = acc / rs[row]  (fp32, z-batched)      (PV -> d_out)
// EPI 5: outb = bf16(acc)      (z-batched)            (V'^T = Wproj@input^T)

template <int EPI>
__global__ __launch_bounds__(256)
void gemm_bt(const u16* __restrict__ A, const u16* __restrict__ A1,
             const u16* __restrict__ B, const u16* __restrict__ B1,
             int lda, int ldb, int K, int ldc,
             u16* __restrict__ outb, u16* __restrict__ outb1,
             float* __restrict__ outf, float* __restrict__ outf1,
             float sq, float sk,
             const float* __restrict__ rs, const float* __restrict__ rs1,
             u16* __restrict__ Pcq, u16* __restrict__ Pqc,
             float* __restrict__ rowsum) {
  __shared__ __align__(16) u16 sA[128 * 64];
  __shared__ __align__(16) u16 sB[128 * 64];
  const int tid = threadIdx.x;
  const int lane = tid & 63;
  const int wave = tid >> 6;
  const int wr = (wave >> 1) * 64;
  const int wc = (wave & 1) * 64;
  const int ar = lane & 15;
  const int by = blockIdx.y, bx = blockIdx.x;
  const int z = blockIdx.z;

  const u16* Ab = (z ? A1 : A) + (size_t)(by * 128) * lda;
  const u16* Bb = (z ? B1 : B) + (size_t)(bx * 128) * ldb;

  f32x4 zero = {0.0f, 0.0f, 0.0f, 0.0f};
  f32x4 acc[4][4];
#pragma unroll
  for (int i = 0; i < 4; ++i)
#pragma unroll
    for (int j = 0; j < 4; ++j) acc[i][j] = zero;

  const int sr = tid >> 3;                        // 0..31 (row within 32-row group)
  const int scL = (tid & 7) << 3;                 // LDS dst col (lane*16B forced)
  const int scG = ((tid & 7) ^ (sr & 7)) << 3;    // swizzled global col granule

  // Hoisted loop-invariant LDS fragment byte offsets (see R5).
  const int l7 = lane & 7, l16 = lane >> 4;
  const int p0b = (l16 ^ l7) << 4;
  const int offA0 = (wr + ar) * 128 + p0b;
  const int offB0 = (wc + ar) * 128 + p0b;
  const char* sAc = (const char*)sA;
  const char* sBc = (const char*)sB;

  for (int k0 = 0; k0 < K; k0 += 64) {
#pragma unroll
    for (int it = 0; it < 4; ++it) {
      int r = it * 32 + sr;
      __builtin_amdgcn_global_load_lds(
          (__attribute__((address_space(1))) void*)(Ab + (size_t)r * lda + k0 + scG),
          (__attribute__((address_space(3))) void*)(sA + r * 64 + scL), 16, 0, 0);
    }
#pragma unroll
    for (int it = 0; it < 4; ++it) {
      int r = it * 32 + sr;
      __builtin_amdgcn_global_load_lds(
          (__attribute__((address_space(1))) void*)(Bb + (size_t)r * ldb + k0 + scG),
          (__attribute__((address_space(3))) void*)(sB + r * 64 + scL), 16, 0, 0);
    }
    __syncthreads();
#pragma unroll
    for (int half = 0; half < 2; ++half) {
      const int px = half ? 64 : 0;
      bf16x8 af[4], bfr[4];
#pragma unroll
      for (int t = 0; t < 4; ++t)
        af[t] = *(const bf16x8*)(sAc + ((offA0 ^ px) + t * 2048));
#pragma unroll
      for (int t = 0; t < 4; ++t)
        bfr[t] = *(const bf16x8*)(sBc + ((offB0 ^ px) + t * 2048));
#pragma unroll
      for (int tm = 0; tm < 4; ++tm)
#pragma unroll
        for (int tn = 0; tn < 4; ++tn)
          acc[tm][tn] = __builtin_amdgcn_mfma_f32_16x16x32_bf16(
              af[tm], bfr[tn], acc[tm][tn], 0, 0, 0);
    }
    __syncthreads();
  }
  // after this barrier sA/sB are dead -> EPI1 reuses sA as scratch.

  // Epilogue. C/D layout (m89): row=(lane>>4)*4+reg, col=lane&15.
  const int qr = (lane >> 4) * 4;
  const int qc = lane & 15;

  if constexpr (EPI == 0) {
#pragma unroll
    for (int tm = 0; tm < 4; ++tm)
#pragma unroll
      for (int r = 0; r < 4; ++r) {
        int row = by * 128 + wr + tm * 16 + qr + r;
#pragma unroll
        for (int tn = 0; tn < 4; ++tn) {
          int col = bx * 128 + wc + tn * 16 + qc;
          float sc = (col < 1024) ? sq : sk;
          outb[(size_t)row * ldc + col] = f2b(acc[tm][tn][r] * sc);
        }
      }
  } else if constexpr (EPI == 1) {
    const bool top = (by < 32);
    const bool left = (bx < 32);
    u16* pdst = nullptr;
    if (top && !left) pdst = Pcq;
    if (!top && left) pdst = Pqc;
    const int growb = by * 128 + wr;               // global row base of this wave
    const int rbase = growb - (top ? 0 : 4096);    // quadrant-local row base
    const int cbase = bx * 128 + wc - (left ? 0 : 4096);
    u16* wbuf = sA + wave * 1152;                  // 16 rows x 72 stride, wave-private
#pragma unroll
    for (int tm = 0; tm < 4; ++tm) {
      float e[4][4];
      float rsum[4] = {0.f, 0.f, 0.f, 0.f};
#pragma unroll
      for (int tn = 0; tn < 4; ++tn)
#pragma unroll
        for (int r = 0; r < 4; ++r) {
          e[tn][r] = exp2_hw(acc[tm][tn][r]);  // scores pre-scaled by log2(e)
          rsum[r] += e[tn][r];
        }
#pragma unroll
      for (int r = 0; r < 4; ++r) {
        float v = rsum[r];
        v += __shfl_xor(v, 1);
        v += __shfl_xor(v, 2);
        v += __shfl_xor(v, 4);
        v += __shfl_xor(v, 8);
        if ((lane & 15) == 0)
          atomicAdd(&rowsum[growb + tm * 16 + qr + r], v);
      }
      if (pdst) {
        // stage 16x64 bf16 slice in LDS (stride 72 spreads banks), then
        // read back 8 rows x 128B and store coalesced 16B/lane.
        // Same-wave DS ops are in-order; no barrier needed.
#pragma unroll
        for (int tn = 0; tn < 4; ++tn)
#pragma unroll
          for (int r = 0; r < 4; ++r)
            wbuf[(qr + r) * 72 + tn * 16 + qc] = f2b(e[tn][r]);
        asm volatile("" ::: "memory");
#pragma unroll
        for (int p = 0; p < 2; ++p) {
          int lr = p * 8 + (lane >> 3);
          int lc = (lane & 7) * 8;
          bf16x8 vv = *(const bf16x8*)(wbuf + lr * 72 + lc);
          *(bf16x8*)(pdst + (size_t)(rbase + tm * 16 + lr) * 4096 + cbase + lc) = vv;
        }
        asm volatile("" ::: "memory");
      }
    }
  } else if constexpr (EPI == 4) {
    float* of = z ? outf1 : outf;
    const float* rsz = z ? rs1 : rs;
#pragma unroll
    for (int tm = 0; tm < 4; ++tm)
#pragma unroll
      for (int r = 0; r < 4; ++r) {
        int row = by * 128 + wr + tm * 16 + qr + r;
        float inv = 1.0f / rsz[row];
#pragma unroll
        for (int tn = 0; tn < 4; ++tn) {
          int col = bx * 128 + wc + tn * 16 + qc;
          of[(size_t)row * ldc + col] = acc[tm][tn][r] * inv;
        }
      }
  } else {  // EPI 5
    u16* ob = z ? outb1 : outb;
#pragma unroll
    for (int tm = 0; tm < 4; ++tm)
#pragma unroll
      for (int r = 0; r < 4; ++r) {
        int row = by * 128 + wr + tm * 16 + qr + r;
#pragma unroll
        for (int tn = 0; tn < 4; ++tn) {
          int col = bx * 128 + wc + tn * 16 + qc;
          ob[(size_t)row * ldc + col] = f2b(acc[tm][tn][r]);
        }
      }
  }
}

// ---------------- launcher ----------------

extern "C" void kernel_launch(void* const* d_in, const int* in_sizes, int n_in,
                              void* d_out, int out_size, void* d_ws, size_t ws_size,
                              hipStream_t stream) {
  (void)in_sizes; (void)n_in; (void)out_size; (void)ws_size;
  const float* query = (const float*)d_in[0];
  const float* s     = (const float*)d_in[1];
  const float* tg    = (const float*)d_in[2];
  const float* Wqkv  = (const float*)d_in[3];
  const float* Wps   = (const float*)d_in[4];
  const float* Wpq   = (const float*)d_in[5];
  float* out = (float*)d_out;

  char* ws = (char*)d_ws;
  u16* cB     = (u16*)ws; ws += (size_t)8192 * 1024 * 2;   // [s+tg ; query] bf16
  u16* sBf    = (u16*)ws; ws += (size_t)4096 * 1024 * 2;   // s bf16
  u16* qks    = (u16*)ws; ws += (size_t)8192 * 2048 * 2;   // [q*SCALE*LOG2E | k*SCALE]
  u16* WqkB   = (u16*)ws; ws += (size_t)2048 * 1024 * 2;
  u16* WpsB   = (u16*)ws; ws += (size_t)1024 * 1024 * 2;
  u16* WpqB   = (u16*)ws; ws += (size_t)1024 * 1024 * 2;
  u16* VsT    = (u16*)ws; ws += (size_t)1024 * 4096 * 2;   // (query@Wps^T)^T
  u16* VqT    = (u16*)ws; ws += (size_t)1024 * 4096 * 2;   // (s@Wpq^T)^T
  u16* Pcq    = (u16*)ws; ws += (size_t)4096 * 4096 * 2;
  u16* Pqc    = (u16*)ws; ws += (size_t)4096 * 4096 * 2;
  float* rowsum = (float*)ws;  // 8192 floats

  const u16* qBf = cB + (size_t)4096 * 1024;  // query bf16 rows of cB

  const float SCALE = 0.17677669529663687f;   // 1024^-0.25
  const float LOG2E = 1.4426950408889634f;

  (void)hipMemsetAsync(rowsum, 0, 8192 * sizeof(float), stream);
  prep_c<<<4096, 256, 0, stream>>>(query, s, tg, cB, sBf);
  conv3<<<2048, 256, 0, stream>>>(Wqkv, Wps, Wpq, WqkB, WpsB, WpqB);

  // V'^T pair: VsT = Wps@query^T, VqT = Wpq@s^T  (M=1024,N=4096,K=1024)
  gemm_bt<5><<<dim3(32, 8, 2), 256, 0, stream>>>(
      WpsB, WpqB, qBf, sBf, 1024, 1024, 1024, 4096,
      VsT, VqT, nullptr, nullptr, 0.f, 0.f,
      nullptr, nullptr, nullptr, nullptr, nullptr);
  // GEMM1: qks[8192,2048] = cB @ WqkB^T; q cols scaled SCALE*LOG2E, k cols SCALE
  gemm_bt<0><<<dim3(16, 64), 256, 0, stream>>>(
      cB, nullptr, WqkB, nullptr, 1024, 1024, 1024, 2048,
      qks, nullptr, nullptr, nullptr, SCALE * LOG2E, SCALE,
      nullptr, nullptr, nullptr, nullptr, nullptr);
  // GEMM2: scores (8192x8192) -> 2^score quadrants (bf16) + row sums
  gemm_bt<1><<<dim3(64, 64), 256, 0, stream>>>(
      qks, nullptr, qks + 1024, nullptr, 2048, 2048, 1024, 0,
      nullptr, nullptr, nullptr, nullptr, 0.f, 0.f,
      nullptr, nullptr, Pcq, Pqc, rowsum);
  // PV (z-batched), fp32 straight to d_out: x_s = (Pcq@V's)/rs ; x_q = (Pqc@V'q)/rs
  gemm_bt<4><<<dim3(8, 32, 2), 256, 0, stream>>>(
      Pcq, Pqc, VsT, VqT, 4096, 4096, 4096, 1024,
      nullptr, nullptr, out, out + (size_t)4096 * 1024, 0.f, 0.f,
      rowsum, rowsum + 4096, nullptr, nullptr, nullptr);
}